// Round 11
// baseline (386.503 us; speedup 1.0000x reference)
//
#include <hip/hip_runtime.h>
#include <stdint.h>

#define KDIM 1024

typedef float  f32x4  __attribute__((ext_vector_type(4)));
typedef short  bf16x8 __attribute__((ext_vector_type(8)));
typedef unsigned short u16;
typedef unsigned int   u32;
typedef u16    u16x8  __attribute__((ext_vector_type(8)));

__device__ __forceinline__ float b2f(u16 u){ u32 x = ((u32)u)<<16; return __builtin_bit_cast(float, x); }
__device__ __forceinline__ u16  f2b(float f){
  u32 u = __builtin_bit_cast(u32, f);
  return (u16)((u + 0x7fffu + ((u>>16)&1u))>>16);   // RNE
}
__device__ __forceinline__ u32 pk2(float a, float b){ return (u32)f2b(a) | ((u32)f2b(b)<<16); }

__device__ __forceinline__ void gload16(const void* g, void* l){
  __builtin_amdgcn_global_load_lds(
      (const __attribute__((address_space(1))) void*)g,
      (__attribute__((address_space(3))) void*)l, 16, 0, 0);
}

// end-of-phase barrier: drain this wave's LDS reads BEFORE crossing (rule #18:
// hipcc may sink reg-only MFMAs + their lgkmcnt below inline-asm barriers;
// sched_barrier(0) pins order; lgkmcnt(0) makes the read-retire explicit so
// the next phase's global_load_lds overwrite can't race pending ds_reads).
__device__ __forceinline__ void phase_bar(){
  __builtin_amdgcn_sched_barrier(0);
  asm volatile("s_waitcnt lgkmcnt(0)" ::: "memory");
  __builtin_amdgcn_sched_barrier(0);
  __builtin_amdgcn_s_barrier();
  __builtin_amdgcn_sched_barrier(0);
}

// ---------------- fp32 -> bf16 convert (8 elems/thread) ----------------
__global__ void k_cvt(const float* __restrict__ in, u16* __restrict__ out, int n8){
  int i = blockIdx.x*256 + threadIdx.x;
  if (i >= n8) return;
  const float4* p = (const float4*)in + (i<<1);
  float4 a = p[0], b = p[1];
  u16x8 o;
  o[0]=f2b(a.x); o[1]=f2b(a.y); o[2]=f2b(a.z); o[3]=f2b(a.w);
  o[4]=f2b(b.x); o[5]=f2b(b.y); o[6]=f2b(b.z); o[7]=f2b(b.w);
  *((u16x8*)out + i) = o;
}

// ------------- fp32 [R][C] -> bf16 [C][R] convert+transpose -------------
__global__ void k_cvtT(const float* __restrict__ in, u16* __restrict__ out, int R, int C){
  __shared__ float t[32][33];
  int tx = threadIdx.x & 31, ty = threadIdx.x >> 5;   // 32x8
  int c0 = blockIdx.x<<5, r0 = blockIdx.y<<5;
  #pragma unroll
  for (int j=0;j<32;j+=8) t[ty+j][tx] = in[(r0+ty+j)*C + c0+tx];
  __syncthreads();
  #pragma unroll
  for (int j=0;j<32;j+=8) out[(c0+ty+j)*R + r0+tx] = f2b(t[tx][ty+j]);
}

// stage one 16KB unit (2 groups of 8 rows per call): each thread issues 2
// gload_lds; global source pre-swizzled (c8 ^ row&7), LDS dest linear.
__device__ __forceinline__ void stage2(const u16* __restrict__ src, int rowbase, int kt,
                                       u16* lbuf, int grp0, int grp1, int lane){
  int r7 = lane >> 3;
  int c8 = (lane & 7) ^ r7;              // row&7 == r7 (groups are 8-row aligned)
  const u16* s0 = src + (size_t)(rowbase + (grp0<<3) + r7)*KDIM + kt + (c8<<3);
  const u16* s1 = src + (size_t)(rowbase + (grp1<<3) + r7)*KDIM + kt + (c8<<3);
  gload16(s0, (char*)lbuf + (grp0<<10));
  gload16(s1, (char*)lbuf + (grp1<<10));
}

// ---------------- bf16 GEMM: C[M,N] = A[M,K] * Bt[N,K]^T + bias ----------------
// 256x256 tile, BK=64, 8 waves (2Mx4N), deep pipeline: 4 phases/K-tile, one
// 16KB stage-unit issued per phase, one counted vmcnt(6) per K-tile (never 0
// in steady state), raw s_barrier + explicit lgkmcnt drain (phase_bar).
// Unit lifetimes: SA0 = A rows{0-63,128-191} (read ph0, restaged ph1 for t+2),
// SA1 = A rows{64-127,192-255} (read ph2, restaged ph0 for t+1), SB0 = B rows
// {0-31,64-95,128-159,192-223} (read ph0, restaged ph2), SB1 = complement
// (read ph1, restaged ph3). vmcnt(6) at ph3 leaves exactly {SA0,SB0,SB1}[t+2]
// in flight => tile t+1 fully landed before its first read.
template<int EPI>
__global__ __launch_bounds__(512, 2) void k_gemm(const u16* __restrict__ A, const u16* __restrict__ Bt,
    const float* __restrict__ bias, u16* __restrict__ oq, u16* __restrict__ ok2, u16* __restrict__ ov,
    float* __restrict__ of, int ntn)
{
  __shared__ u16 ldsb[2][2][256*64];     // [buf][A=0/B=1][row*64+col], 128 KiB
  const int t = threadIdx.x, lane = t & 63, wid = t >> 6;
  const int l15 = lane & 15, g = lane >> 4;
  const int wr = wid >> 2, wc = wid & 3;

  // bijective XCD swizzle, m-major tile order (per-XCD contiguous A panel)
  const int nwg = gridDim.x, cpx = nwg >> 3, bid = blockIdx.x;
  const int swz = (bid & 7)*cpx + (bid >> 3);
  const int mt = swz / ntn, nt = swz % ntn;
  const int m0 = mt << 8, n0 = nt << 8;

  const f32x4 fz = {0.f,0.f,0.f,0.f};
  f32x4 acc[8][4];
  #pragma unroll
  for (int m=0;m<8;m++)
    #pragma unroll
    for (int n=0;n<4;n++) acc[m][n] = fz;

  const int NT = KDIM / 64;              // 16
  // SB0 group patterns per wid
  const int sb0g0 = (wid<4)? wid    : wid+4;
  const int sb0g1 = (wid<4)? wid+16 : wid+20;
  const int sb1g0 = sb0g0 + 4, sb1g1 = sb0g1 + 4;

  // ---- prologue: tile0 complete + {SA0,SB0,SB1}[1] ----
  stage2(A,  m0, 0,  ldsb[0][0], wid,   wid+16, lane);   // SA0[0]
  stage2(A,  m0, 0,  ldsb[0][0], wid+8, wid+24, lane);   // SA1[0]
  stage2(Bt, n0, 0,  ldsb[0][1], sb0g0, sb0g1,  lane);   // SB0[0]
  stage2(Bt, n0, 0,  ldsb[0][1], sb1g0, sb1g1,  lane);   // SB1[0]
  stage2(A,  m0, 64, ldsb[1][0], wid,   wid+16, lane);   // SA0[1]
  stage2(Bt, n0, 64, ldsb[1][1], sb0g0, sb0g1,  lane);   // SB0[1]
  stage2(Bt, n0, 64, ldsb[1][1], sb1g0, sb1g1,  lane);   // SB1[1]
  __builtin_amdgcn_sched_barrier(0);
  asm volatile("s_waitcnt vmcnt(6) lgkmcnt(0)" ::: "memory");
  __builtin_amdgcn_sched_barrier(0);
  __builtin_amdgcn_s_barrier();
  __builtin_amdgcn_sched_barrier(0);

  for (int tt = 0; tt < NT; ++tt) {
    const int b = tt & 1;
    const char* cA = (const char*)ldsb[b][0];
    const char* cB = (const char*)ldsb[b][1];
    u16* nA1 = ldsb[b^1][0];
    u16* nA2 = ldsb[b][0];
    u16* nB2 = ldsb[b][1];
    const int kt1 = (tt+1) << 6, kt2 = (tt+2) << 6;

    bf16x8 af[4][2], b0[2][2], b1[2][2];

    // ---- phase 0: stage SA1[t+1]; read A(mh0)+B(nh0); MFMA q00 ----
    if (tt + 1 < NT) stage2(A, m0, kt1, nA1, wid+8, wid+24, lane);
    #pragma unroll
    for (int mf=0; mf<4; mf++)
      #pragma unroll
      for (int ks=0; ks<2; ks++){
        int row = (wr<<7) + (mf<<4) + l15, c8 = (ks<<2) + g;
        af[mf][ks] = *(const bf16x8*)(cA + (row<<7) + ((c8 ^ (row&7))<<4));
      }
    #pragma unroll
    for (int nf=0; nf<2; nf++)
      #pragma unroll
      for (int ks=0; ks<2; ks++){
        int row = (wc<<6) + (nf<<4) + l15, c8 = (ks<<2) + g;
        b0[nf][ks] = *(const bf16x8*)(cB + (row<<7) + ((c8 ^ (row&7))<<4));
      }
    __builtin_amdgcn_s_setprio(1);
    #pragma unroll
    for (int mf=0; mf<4; mf++)
      #pragma unroll
      for (int nf=0; nf<2; nf++)
        #pragma unroll
        for (int ks=0; ks<2; ks++)
          acc[mf][nf] = __builtin_amdgcn_mfma_f32_16x16x32_bf16(af[mf][ks], b0[nf][ks], acc[mf][nf], 0,0,0);
    __builtin_amdgcn_s_setprio(0);
    phase_bar();

    // ---- phase 1: stage SA0[t+2]; read B(nh1); MFMA q01 ----
    if (tt + 2 < NT) stage2(A, m0, kt2, nA2, wid, wid+16, lane);
    #pragma unroll
    for (int nf=0; nf<2; nf++)
      #pragma unroll
      for (int ks=0; ks<2; ks++){
        int row = (wc<<6) + ((nf+2)<<4) + l15, c8 = (ks<<2) + g;
        b1[nf][ks] = *(const bf16x8*)(cB + (row<<7) + ((c8 ^ (row&7))<<4));
      }
    __builtin_amdgcn_s_setprio(1);
    #pragma unroll
    for (int mf=0; mf<4; mf++)
      #pragma unroll
      for (int nf=0; nf<2; nf++)
        #pragma unroll
        for (int ks=0; ks<2; ks++)
          acc[mf][nf+2] = __builtin_amdgcn_mfma_f32_16x16x32_bf16(af[mf][ks], b1[nf][ks], acc[mf][nf+2], 0,0,0);
    __builtin_amdgcn_s_setprio(0);
    phase_bar();

    // ---- phase 2: stage SB0[t+2]; read A(mh1); MFMA q10 ----
    if (tt + 2 < NT) stage2(Bt, n0, kt2, nB2, sb0g0, sb0g1, lane);
    #pragma unroll
    for (int mf=0; mf<4; mf++)
      #pragma unroll
      for (int ks=0; ks<2; ks++){
        int row = (wr<<7) + ((mf+4)<<4) + l15, c8 = (ks<<2) + g;
        af[mf][ks] = *(const bf16x8*)(cA + (row<<7) + ((c8 ^ (row&7))<<4));
      }
    __builtin_amdgcn_s_setprio(1);
    #pragma unroll
    for (int mf=0; mf<4; mf++)
      #pragma unroll
      for (int nf=0; nf<2; nf++)
        #pragma unroll
        for (int ks=0; ks<2; ks++)
          acc[mf+4][nf] = __builtin_amdgcn_mfma_f32_16x16x32_bf16(af[mf][ks], b0[nf][ks], acc[mf+4][nf], 0,0,0);
    __builtin_amdgcn_s_setprio(0);
    phase_bar();

    // ---- phase 3: stage SB1[t+2]; MFMA q11; counted vmcnt ----
    if (tt + 2 < NT) stage2(Bt, n0, kt2, nB2, sb1g0, sb1g1, lane);
    __builtin_amdgcn_s_setprio(1);
    #pragma unroll
    for (int mf=0; mf<4; mf++)
      #pragma unroll
      for (int nf=0; nf<2; nf++)
        #pragma unroll
        for (int ks=0; ks<2; ks++)
          acc[mf+4][nf+2] = __builtin_amdgcn_mfma_f32_16x16x32_bf16(af[mf][ks], b1[nf][ks], acc[mf+4][nf+2], 0,0,0);
    __builtin_amdgcn_s_setprio(0);
    __builtin_amdgcn_sched_barrier(0);
    if (tt + 2 < NT) { asm volatile("s_waitcnt vmcnt(6) lgkmcnt(0)" ::: "memory"); }
    else             { asm volatile("s_waitcnt vmcnt(0) lgkmcnt(0)" ::: "memory"); }
    __builtin_amdgcn_sched_barrier(0);
    __builtin_amdgcn_s_barrier();
    __builtin_amdgcn_sched_barrier(0);
  }

  if (EPI == 0) {
    const int which = n0 >> 10;
    u16* dst = (which==0) ? oq : (which==1) ? ok2 : ov;
    #pragma unroll
    for (int nf=0; nf<4; nf++){
      int n_g = n0 + (wc<<6) + (nf<<4) + l15;
      float bv = bias[n_g];
      int h = (n_g >> 6) & 15, d = n_g & 63;
      #pragma unroll
      for (int mf=0; mf<8; mf++){
        int mg = m0 + (wr<<7) + (mf<<4) + (g<<2);
        #pragma unroll
        for (int j=0;j<4;j++){
          int m_g = mg + j;
          int bb = m_g >> 9, p = m_g & 511;
          dst[((bb*16 + h)*512 + p)*64 + d] = f2b(acc[mf][nf][j] + bv);
        }
      }
    }
  } else {
    #pragma unroll
    for (int nf=0; nf<4; nf++){
      int n_g = n0 + (wc<<6) + (nf<<4) + l15;
      float bv = bias[n_g];
      #pragma unroll
      for (int mf=0; mf<8; mf++){
        int mg = m0 + (wr<<7) + (mf<<4) + (g<<2);
        #pragma unroll
        for (int j=0;j<4;j++)
          of[(size_t)(mg+j)*1024 + n_g] = acc[mf][nf][j] + bv;
      }
    }
  }
}

// -------- V (b,h,p,d) -> V^T (b,h,d,p), bf16, 64x64 tiles --------
__global__ void k_vt(const u16* __restrict__ v, u16* __restrict__ vt){
  __shared__ u16 tl[64][65];
  const int bh = blockIdx.y, p0 = blockIdx.x << 6;
  const int t = threadIdx.x;
  #pragma unroll
  for (int i=0;i<4;i++){
    int e4 = (i<<8) + t;
    int r = e4 >> 4, c = (e4 & 15) << 2;
    ushort4 x = *(const ushort4*)&v[((bh<<9) + p0 + r)*64 + c];
    tl[r][c+0]=x.x; tl[r][c+1]=x.y; tl[r][c+2]=x.z; tl[r][c+3]=x.w;
  }
  __syncthreads();
  #pragma unroll
  for (int i=0;i<4;i++){
    int e4 = (i<<8) + t;
    int d = e4 >> 4, c = (e4 & 15) << 2;
    ushort4 x;
    x.x = tl[c+0][d]; x.y = tl[c+1][d]; x.z = tl[c+2][d]; x.w = tl[c+3][d];
    *(ushort4*)&vt[((bh<<6) + d)*512 + p0 + c] = x;
  }
}

// ---------------- flash attention (unchanged from round 1, verified) ----------------
__global__ __launch_bounds__(256, 2) void k_attn(const u16* __restrict__ q, const u16* __restrict__ k,
                                                 const u16* __restrict__ vt, u16* __restrict__ z)
{
  __shared__ u16 lK[64*64];
  __shared__ u16 lV[64*64];
  __shared__ u16 lP[4][64*64];
  const int t = threadIdx.x, lane = t & 63, wid = t >> 6;
  const int l15 = lane & 15, g = lane >> 4;
  const int bh = blockIdx.x >> 1, qt = blockIdx.x & 1;
  const int bb = bh >> 4, h = bh & 15;
  const int q0 = (qt<<8) + (wid<<6);
  const float cs = 0.18033688011112042f;   // log2(e)/sqrt(64), prefolded into Q

  bf16x8 qf[4][2];
  #pragma unroll
  for (int mf=0; mf<4; mf++)
    #pragma unroll
    for (int ks=0; ks<2; ks++){
      bf16x8 vq = *(const bf16x8*)(q + ((bh<<9) + q0 + (mf<<4) + l15)*64 + (ks<<5) + (g<<3));
      #pragma unroll
      for (int j=0;j<8;j++) vq[j] = (short)f2b(b2f((u16)vq[j]) * cs);
      qf[mf][ks] = vq;
    }

  const f32x4 fz = {0.f,0.f,0.f,0.f};
  f32x4 zt[4][4];
  #pragma unroll
  for (int df=0;df<4;df++)
    #pragma unroll
    for (int mf=0;mf<4;mf++) zt[df][mf] = fz;
  float mrun[4], lrun[4];
  #pragma unroll
  for (int mf=0;mf<4;mf++){ mrun[mf] = -__builtin_inff(); lrun[mf] = 0.f; }

  for (int kv0 = 0; kv0 < 512; kv0 += 64) {
    __syncthreads();
    #pragma unroll
    for (int i=0;i<2;i++){
      int s = (i<<8) + t;
      int row = s >> 3;
      int c8 = (s & 7) ^ (row & 7);
      gload16(k  + ((bh<<9) + kv0 + row)*64 + (c8<<3), (char*)lK + (((i<<2)+wid)<<10));
    }
    #pragma unroll
    for (int i=0;i<2;i++){
      int s = (i<<8) + t;
      int row = s >> 3;
      int c8 = (s & 7) ^ (row & 7);
      gload16(vt + ((bh<<6) + row)*512 + kv0 + (c8<<3), (char*)lV + (((i<<2)+wid)<<10));
    }
    __syncthreads();

    f32x4 sc[4][4];
    #pragma unroll
    for (int nf=0;nf<4;nf++)
      #pragma unroll
      for (int mf=0;mf<4;mf++) sc[nf][mf] = fz;
    #pragma unroll
    for (int ks=0; ks<2; ks++){
      const int c8 = (ks<<2) + g;
      bf16x8 kf[4];
      #pragma unroll
      for (int nf=0;nf<4;nf++){
        int row = (nf<<4) + l15;
        kf[nf] = *(const bf16x8*)((const char*)lK + (row<<7) + ((c8 ^ (row&7))<<4));
      }
      #pragma unroll
      for (int nf=0;nf<4;nf++)
        #pragma unroll
        for (int mf=0;mf<4;mf++)
          sc[nf][mf] = __builtin_amdgcn_mfma_f32_16x16x32_bf16(kf[nf], qf[mf][ks], sc[nf][mf], 0,0,0);
    }

    #pragma unroll
    for (int mf=0;mf<4;mf++){
      float pm = -__builtin_inff();
      #pragma unroll
      for (int nf=0;nf<4;nf++)
        #pragma unroll
        for (int j=0;j<4;j++) pm = fmaxf(pm, sc[nf][mf][j]);
      pm = fmaxf(pm, __shfl_xor(pm, 16));
      pm = fmaxf(pm, __shfl_xor(pm, 32));
      float mnew = fmaxf(mrun[mf], pm);
      float corr = __builtin_amdgcn_exp2f(mrun[mf] - mnew);
      mrun[mf] = mnew;
      float rs = 0.f;
      #pragma unroll
      for (int nf=0;nf<4;nf++)
        #pragma unroll
        for (int j=0;j<4;j++){
          float pv = __builtin_amdgcn_exp2f(sc[nf][mf][j] - mnew);
          sc[nf][mf][j] = pv; rs += pv;
        }
      rs += __shfl_xor(rs, 16);
      rs += __shfl_xor(rs, 32);
      lrun[mf] = lrun[mf]*corr + rs;
      #pragma unroll
      for (int df=0;df<4;df++){
        zt[df][mf][0]*=corr; zt[df][mf][1]*=corr; zt[df][mf][2]*=corr; zt[df][mf][3]*=corr;
      }
    }

    #pragma unroll
    for (int nf=0;nf<4;nf++)
      #pragma unroll
      for (int mf=0;mf<4;mf++){
        int qr = (mf<<4) + l15;
        int c8 = (nf<<1) + (g>>1);
        uint2 w2; w2.x = pk2(sc[nf][mf][0], sc[nf][mf][1]);
        w2.y = pk2(sc[nf][mf][2], sc[nf][mf][3]);
        *(uint2*)((char*)lP[wid] + (qr<<7) + ((c8 ^ (qr&7))<<4) + ((g&1)<<3)) = w2;
      }
    asm volatile("s_waitcnt lgkmcnt(0)" ::: "memory");

    #pragma unroll
    for (int ks=0; ks<2; ks++){
      const int c8 = (ks<<2) + g;
      bf16x8 vf[4], pf[4];
      #pragma unroll
      for (int df=0;df<4;df++){
        int row = (df<<4) + l15;
        vf[df] = *(const bf16x8*)((const char*)lV + (row<<7) + ((c8 ^ (row&7))<<4));
      }
      #pragma unroll
      for (int mf=0;mf<4;mf++){
        int qr = (mf<<4) + l15;
        pf[mf] = *(const bf16x8*)((const char*)lP[wid] + (qr<<7) + ((c8 ^ (qr&7))<<4));
      }
      #pragma unroll
      for (int df=0;df<4;df++)
        #pragma unroll
        for (int mf=0;mf<4;mf++)
          zt[df][mf] = __builtin_amdgcn_mfma_f32_16x16x32_bf16(vf[df], pf[mf], zt[df][mf], 0,0,0);
    }
  }

  #pragma unroll
  for (int mf=0;mf<4;mf++){
    float inv = 1.0f / lrun[mf];
    int qr = (mf<<4) + l15;
    int pg = (qt<<8) + (wid<<6) + qr;
    #pragma unroll
    for (int df=0;df<4;df++){
      int d0 = (df<<4) + (g<<2);
      ushort4 o;
      o.x = f2b(zt[df][mf][0]*inv);
      o.y = f2b(zt[df][mf][1]*inv);
      o.z = f2b(zt[df][mf][2]*inv);
      o.w = f2b(zt[df][mf][3]*inv);
      *(ushort4*)&z[ (((bb<<9) + pg)*16 + h)*64 + d0 ] = o;
    }
  }
}

extern "C" void kernel_launch(void* const* d_in, const int* in_sizes, int n_in,
                              void* d_out, int out_size, void* d_ws, size_t ws_size,
                              hipStream_t stream)
{
  (void)in_sizes; (void)n_in; (void)out_size; (void)ws_size;
  const float* x    = (const float*)d_in[0];
  const float* wqkv = (const float*)d_in[1];
  const float* bqkv = (const float*)d_in[2];
  const float* wout = (const float*)d_in[3];
  const float* bout = (const float*)d_in[4];
  float* out = (float*)d_out;
  char* w = (char*)d_ws;

  u16* wqT = (u16*)(w + 0);          //  6.29 MB  w_qkv^T bf16 [3072][1024]
  u16* woT = (u16*)(w + 6291456);    //  2.10 MB  w_out^T bf16 [1024][1024]
  u16* xb  = (u16*)(w + 8388608);    // 33.55 MB  x bf16       (later: V^T)
  u16* vtb = xb;
  u16* qb  = (u16*)(w + 41943040);   // 33.55 MB  Q (b,h,p,d)
  u16* kb  = (u16*)(w + 75497472);   // 33.55 MB  K (b,h,p,d)
  u16* vb  = (u16*)(w + 109051904);  // 33.55 MB  V (b,h,p,d)  (later: Z (b,p,h,d))
  u16* zb  = vb;

  k_cvt <<<dim3(8192),    dim3(256), 0, stream>>>(x, xb, 2097152);
  k_cvtT<<<dim3(96, 32),  dim3(256), 0, stream>>>(wqkv, wqT, 1024, 3072);
  k_cvtT<<<dim3(32, 32),  dim3(256), 0, stream>>>(wout, woT, 1024, 1024);
  k_gemm<0><<<dim3(768), dim3(512), 0, stream>>>(xb, wqT, bqkv, qb, kb, vb, nullptr, 12);
  k_vt  <<<dim3(8, 512),  dim3(256), 0, stream>>>(vb, vtb);
  k_attn<<<dim3(1024),    dim3(256), 0, stream>>>(qb, kb, vtb, zb);
  k_gemm<1><<<dim3(256), dim3(512), 0, stream>>>(zb, woT, bout, nullptr, nullptr, nullptr, out, 4);
}

// Round 12
// 369.702 us; speedup vs baseline: 1.0454x; 1.0454x over previous
//
#include <hip/hip_runtime.h>
#include <stdint.h>

#define KDIM 1024

typedef float  f32x4  __attribute__((ext_vector_type(4)));
typedef short  bf16x8 __attribute__((ext_vector_type(8)));
typedef unsigned short u16;
typedef unsigned int   u32;
typedef u16    u16x8  __attribute__((ext_vector_type(8)));

__device__ __forceinline__ float b2f(u16 u){ u32 x = ((u32)u)<<16; return __builtin_bit_cast(float, x); }
__device__ __forceinline__ u16  f2b(float f){
  u32 u = __builtin_bit_cast(u32, f);
  return (u16)((u + 0x7fffu + ((u>>16)&1u))>>16);   // RNE
}
__device__ __forceinline__ u32 pk2(float a, float b){ return (u32)f2b(a) | ((u32)f2b(b)<<16); }

__device__ __forceinline__ void gload16(const void* g, void* l){
  __builtin_amdgcn_global_load_lds(
      (const __attribute__((address_space(1))) void*)g,
      (__attribute__((address_space(3))) void*)l, 16, 0, 0);
}

// fused end-of-tile fence (validated pattern from R6 fix): retire this wave's
// LDS reads AND all outstanding gload_lds before any wave crosses; sched_barrier
// pins order so hipcc can't sink MFMAs/reads past the waitcnt (rule #18).
__device__ __forceinline__ void tile_fence(){
  __builtin_amdgcn_sched_barrier(0);
  asm volatile("s_waitcnt vmcnt(0) lgkmcnt(0)" ::: "memory");
  __builtin_amdgcn_sched_barrier(0);
  __builtin_amdgcn_s_barrier();
  __builtin_amdgcn_sched_barrier(0);
}

// ---------------- fp32 -> bf16 convert (8 elems/thread) ----------------
__global__ void k_cvt(const float* __restrict__ in, u16* __restrict__ out, int n8){
  int i = blockIdx.x*256 + threadIdx.x;
  if (i >= n8) return;
  const float4* p = (const float4*)in + (i<<1);
  float4 a = p[0], b = p[1];
  u16x8 o;
  o[0]=f2b(a.x); o[1]=f2b(a.y); o[2]=f2b(a.z); o[3]=f2b(a.w);
  o[4]=f2b(b.x); o[5]=f2b(b.y); o[6]=f2b(b.z); o[7]=f2b(b.w);
  *((u16x8*)out + i) = o;
}

// ------------- fp32 [R][C] -> bf16 [C][R] convert+transpose -------------
__global__ void k_cvtT(const float* __restrict__ in, u16* __restrict__ out, int R, int C){
  __shared__ float t[32][33];
  int tx = threadIdx.x & 31, ty = threadIdx.x >> 5;   // 32x8
  int c0 = blockIdx.x<<5, r0 = blockIdx.y<<5;
  #pragma unroll
  for (int j=0;j<32;j+=8) t[ty+j][tx] = in[(r0+ty+j)*C + c0+tx];
  __syncthreads();
  #pragma unroll
  for (int j=0;j<32;j+=8) out[(c0+ty+j)*R + r0+tx] = f2b(t[tx][ty+j]);
}

// ---------------- bf16 GEMM (REVERTED to R1 measured-good: 102 us, MfmaUtil 45%,
// 0 bank conflicts, 3 blocks/CU). 128x128 tile, BK=64, 4 waves (2x2),
// 16x16x32 MFMA, XOR-swizzled LDS via pre-swizzled global source.
// EPI==0: bf16 out, scatter to q/k/v (b,h,p,d). EPI==1: fp32 out [M][1024].
template<int EPI>
__global__ __launch_bounds__(256, 3) void k_gemm(const u16* __restrict__ A, const u16* __restrict__ Bt,
    const float* __restrict__ bias, u16* __restrict__ oq, u16* __restrict__ ok2, u16* __restrict__ ov,
    float* __restrict__ of)
{
  __shared__ u16 lA[128*64];
  __shared__ u16 lB[128*64];
  const int t = threadIdx.x, lane = t & 63, wid = t >> 6;
  const int l15 = lane & 15, g = lane >> 4;
  const int m0 = blockIdx.y << 7, n0 = blockIdx.x << 7;
  const int wr = wid >> 1, wc = wid & 1;
  const f32x4 fz = {0.f,0.f,0.f,0.f};
  f32x4 acc[4][4];
  #pragma unroll
  for (int m=0;m<4;m++)
    #pragma unroll
    for (int n=0;n<4;n++) acc[m][n] = fz;

  for (int kt = 0; kt < KDIM; kt += 64) {
    __syncthreads();
    #pragma unroll
    for (int i=0;i<4;i++){
      int s = (i<<8) + t;
      int row = s >> 3;
      int c8 = (s & 7) ^ (row & 7);          // pre-swizzled global source
      gload16(A + (m0 + row)*KDIM + kt + (c8<<3), (char*)lA + (((i<<2) + wid)<<10));
    }
    #pragma unroll
    for (int i=0;i<4;i++){
      int s = (i<<8) + t;
      int row = s >> 3;
      int c8 = (s & 7) ^ (row & 7);
      gload16(Bt + (n0 + row)*KDIM + kt + (c8<<3), (char*)lB + (((i<<2) + wid)<<10));
    }
    __syncthreads();
    #pragma unroll
    for (int ks=0; ks<2; ++ks){
      const int c8 = (ks<<2) + g;
      bf16x8 af[4], bfr[4];
      #pragma unroll
      for (int m=0;m<4;m++){
        int row = (wr<<6) + (m<<4) + l15;
        af[m] = *(const bf16x8*)((const char*)lA + (row<<7) + ((c8 ^ (row&7))<<4));
      }
      #pragma unroll
      for (int n=0;n<4;n++){
        int row = (wc<<6) + (n<<4) + l15;
        bfr[n] = *(const bf16x8*)((const char*)lB + (row<<7) + ((c8 ^ (row&7))<<4));
      }
      #pragma unroll
      for (int m=0;m<4;m++)
        #pragma unroll
        for (int n=0;n<4;n++)
          acc[m][n] = __builtin_amdgcn_mfma_f32_16x16x32_bf16(af[m], bfr[n], acc[m][n], 0,0,0);
    }
  }

  if (EPI == 0) {
    const int which = n0 >> 10;                       // tile lies in one of q/k/v
    u16* dst = (which==0) ? oq : (which==1) ? ok2 : ov;
    #pragma unroll
    for (int n=0;n<4;n++){
      int n_g = n0 + (wc<<6) + (n<<4) + l15;
      float bv = bias[n_g];
      int h = (n_g >> 6) & 15, d = n_g & 63;
      #pragma unroll
      for (int m=0;m<4;m++){
        int mg = m0 + (wr<<6) + (m<<4) + (g<<2);
        #pragma unroll
        for (int j=0;j<4;j++){
          int m_g = mg + j;
          int bb = m_g >> 9, p = m_g & 511;
          dst[((bb*16 + h)*512 + p)*64 + d] = f2b(acc[m][n][j] + bv);
        }
      }
    }
  } else {
    #pragma unroll
    for (int n=0;n<4;n++){
      int n_g = n0 + (wc<<6) + (n<<4) + l15;
      float bv = bias[n_g];
      #pragma unroll
      for (int m=0;m<4;m++){
        int mg = m0 + (wr<<6) + (m<<4) + (g<<2);
        #pragma unroll
        for (int j=0;j<4;j++)
          of[(mg+j)*1024 + n_g] = acc[m][n][j] + bv;
      }
    }
  }
}

// -------- V (b,h,p,d) -> V^T (b,h,d,p), bf16, 64x64 tiles --------
__global__ void k_vt(const u16* __restrict__ v, u16* __restrict__ vt){
  __shared__ u16 tl[64][65];
  const int bh = blockIdx.y, p0 = blockIdx.x << 6;
  const int t = threadIdx.x;
  #pragma unroll
  for (int i=0;i<4;i++){
    int e4 = (i<<8) + t;
    int r = e4 >> 4, c = (e4 & 15) << 2;
    ushort4 x = *(const ushort4*)&v[((bh<<9) + p0 + r)*64 + c];
    tl[r][c+0]=x.x; tl[r][c+1]=x.y; tl[r][c+2]=x.z; tl[r][c+3]=x.w;
  }
  __syncthreads();
  #pragma unroll
  for (int i=0;i<4;i++){
    int e4 = (i<<8) + t;
    int d = e4 >> 4, c = (e4 & 15) << 2;
    ushort4 x;
    x.x = tl[c+0][d]; x.y = tl[c+1][d]; x.z = tl[c+2][d]; x.w = tl[c+3][d];
    *(ushort4*)&vt[((bh<<6) + d)*512 + p0 + c] = x;
  }
}

// ---------------- flash attention: NEW double-buffered K/V staging ----------------
// Change vs R1 (validated): K/V tiles double-buffered; next tile's gload_lds
// issued BEFORE current tile's compute; ONE tile_fence per iteration (was 2
// __syncthreads with fully-exposed load latency). Ledger: iter t reads buf[t&1]
// (staged iter t-1, fenced) and stages buf[(t&1)^1] whose previous readers
// (iter t-1) retired their ds_reads at the same fence (lgkmcnt(0) before
// s_barrier). lP stays wave-private with an in-wave lgkmcnt fence.
__global__ __launch_bounds__(256, 2) void k_attn(const u16* __restrict__ q, const u16* __restrict__ k,
                                                 const u16* __restrict__ vt, u16* __restrict__ z)
{
  __shared__ u16 lK[2][64*64];
  __shared__ u16 lV[2][64*64];
  __shared__ u16 lP[4][64*64];
  const int t = threadIdx.x, lane = t & 63, wid = t >> 6;
  const int l15 = lane & 15, g = lane >> 4;
  const int bh = blockIdx.x >> 1, qt = blockIdx.x & 1;
  const int bb = bh >> 4, h = bh & 15;
  const int q0 = (qt<<8) + (wid<<6);
  const float cs = 0.18033688011112042f;   // log2(e)/sqrt(64), prefolded into Q

  bf16x8 qf[4][2];
  #pragma unroll
  for (int mf=0; mf<4; mf++)
    #pragma unroll
    for (int ks=0; ks<2; ks++){
      bf16x8 vq = *(const bf16x8*)(q + ((bh<<9) + q0 + (mf<<4) + l15)*64 + (ks<<5) + (g<<3));
      #pragma unroll
      for (int j=0;j<8;j++) vq[j] = (short)f2b(b2f((u16)vq[j]) * cs);
      qf[mf][ks] = vq;
    }

  const f32x4 fz = {0.f,0.f,0.f,0.f};
  f32x4 zt[4][4];                 // [df][mf] = Z^T fragments
  #pragma unroll
  for (int df=0;df<4;df++)
    #pragma unroll
    for (int mf=0;mf<4;mf++) zt[df][mf] = fz;
  float mrun[4], lrun[4];
  #pragma unroll
  for (int mf=0;mf<4;mf++){ mrun[mf] = -__builtin_inff(); lrun[mf] = 0.f; }

  // K/V tile staging: pre-swizzled global source, linear wave-chunk LDS dest
  auto stage_kv = [&](int kv0, int bufIdx){
    #pragma unroll
    for (int i=0;i<2;i++){
      int s = (i<<8) + t;
      int row = s >> 3;
      int c8 = (s & 7) ^ (row & 7);
      gload16(k  + ((bh<<9) + kv0 + row)*64 + (c8<<3), (char*)lK[bufIdx] + (((i<<2)+wid)<<10));
    }
    #pragma unroll
    for (int i=0;i<2;i++){
      int s = (i<<8) + t;
      int row = s >> 3;
      int c8 = (s & 7) ^ (row & 7);
      gload16(vt + ((bh<<6) + row)*512 + kv0 + (c8<<3), (char*)lV[bufIdx] + (((i<<2)+wid)<<10));
    }
  };

  // prologue: tile 0 into buf 0
  stage_kv(0, 0);
  tile_fence();

  for (int it = 0; it < 8; ++it) {
    const int cur = it & 1;
    const char* cK = (const char*)lK[cur];
    const char* cV = (const char*)lV[cur];
    // prefetch next tile into the other buffer; lands under this tile's compute
    if (it + 1 < 8) stage_kv((it + 1) << 6, cur ^ 1);

    f32x4 sc[4][4];               // [nf_k][mf_q] = S^T fragments
    #pragma unroll
    for (int nf=0;nf<4;nf++)
      #pragma unroll
      for (int mf=0;mf<4;mf++) sc[nf][mf] = fz;
    #pragma unroll
    for (int ks=0; ks<2; ks++){
      const int c8 = (ks<<2) + g;
      bf16x8 kf[4];
      #pragma unroll
      for (int nf=0;nf<4;nf++){
        int row = (nf<<4) + l15;
        kf[nf] = *(const bf16x8*)(cK + (row<<7) + ((c8 ^ (row&7))<<4));
      }
      #pragma unroll
      for (int nf=0;nf<4;nf++)
        #pragma unroll
        for (int mf=0;mf<4;mf++)
          sc[nf][mf] = __builtin_amdgcn_mfma_f32_16x16x32_bf16(kf[nf], qf[mf][ks], sc[nf][mf], 0,0,0);
    }

    // online softmax; lane owns q-row (mf*16 + l15); k-subsets split over g
    #pragma unroll
    for (int mf=0;mf<4;mf++){
      float pm = -__builtin_inff();
      #pragma unroll
      for (int nf=0;nf<4;nf++)
        #pragma unroll
        for (int j=0;j<4;j++) pm = fmaxf(pm, sc[nf][mf][j]);
      pm = fmaxf(pm, __shfl_xor(pm, 16));
      pm = fmaxf(pm, __shfl_xor(pm, 32));
      float mnew = fmaxf(mrun[mf], pm);
      float corr = __builtin_amdgcn_exp2f(mrun[mf] - mnew);
      mrun[mf] = mnew;
      float rs = 0.f;
      #pragma unroll
      for (int nf=0;nf<4;nf++)
        #pragma unroll
        for (int j=0;j<4;j++){
          float pv = __builtin_amdgcn_exp2f(sc[nf][mf][j] - mnew);
          sc[nf][mf][j] = pv; rs += pv;
        }
      rs += __shfl_xor(rs, 16);
      rs += __shfl_xor(rs, 32);
      lrun[mf] = lrun[mf]*corr + rs;
      #pragma unroll
      for (int df=0;df<4;df++){
        zt[df][mf][0]*=corr; zt[df][mf][1]*=corr; zt[df][mf][2]*=corr; zt[df][mf][3]*=corr;
      }
    }

    // pack P (bf16) -> wave-private swizzled LDS; regs are 4 contiguous k
    #pragma unroll
    for (int nf=0;nf<4;nf++)
      #pragma unroll
      for (int mf=0;mf<4;mf++){
        int qr = (mf<<4) + l15;
        int c8 = (nf<<1) + (g>>1);
        uint2 w2; w2.x = pk2(sc[nf][mf][0], sc[nf][mf][1]);
        w2.y = pk2(sc[nf][mf][2], sc[nf][mf][3]);
        *(uint2*)((char*)lP[wid] + (qr<<7) + ((c8 ^ (qr&7))<<4) + ((g&1)<<3)) = w2;
      }
    __builtin_amdgcn_sched_barrier(0);
    asm volatile("s_waitcnt lgkmcnt(0)" ::: "memory");   // wave-local write->read fence
    __builtin_amdgcn_sched_barrier(0);

    #pragma unroll
    for (int ks=0; ks<2; ks++){
      const int c8 = (ks<<2) + g;
      bf16x8 vf[4], pf[4];
      #pragma unroll
      for (int df=0;df<4;df++){
        int row = (df<<4) + l15;
        vf[df] = *(const bf16x8*)(cV + (row<<7) + ((c8 ^ (row&7))<<4));
      }
      #pragma unroll
      for (int mf=0;mf<4;mf++){
        int qr = (mf<<4) + l15;
        pf[mf] = *(const bf16x8*)((const char*)lP[wid] + (qr<<7) + ((c8 ^ (qr&7))<<4));
      }
      #pragma unroll
      for (int df=0;df<4;df++)
        #pragma unroll
        for (int mf=0;mf<4;mf++)
          zt[df][mf] = __builtin_amdgcn_mfma_f32_16x16x32_bf16(vf[df], pf[mf], zt[df][mf], 0,0,0);
    }

    // one fence per tile: retire our ds_reads (buffer about to be restaged) and
    // the prefetch gloads (buffer about to be read), then block-wide barrier.
    tile_fence();
  }

  // epilogue: z (b,p,h,d) bf16; lane's cols (q) match its lrun
  #pragma unroll
  for (int mf=0;mf<4;mf++){
    float inv = 1.0f / lrun[mf];
    int qr = (mf<<4) + l15;
    int pg = (qt<<8) + (wid<<6) + qr;
    #pragma unroll
    for (int df=0;df<4;df++){
      int d0 = (df<<4) + (g<<2);
      ushort4 o;
      o.x = f2b(zt[df][mf][0]*inv);
      o.y = f2b(zt[df][mf][1]*inv);
      o.z = f2b(zt[df][mf][2]*inv);
      o.w = f2b(zt[df][mf][3]*inv);
      *(ushort4*)&z[ (((bb<<9) + pg)*16 + h)*64 + d0 ] = o;
    }
  }
}

extern "C" void kernel_launch(void* const* d_in, const int* in_sizes, int n_in,
                              void* d_out, int out_size, void* d_ws, size_t ws_size,
                              hipStream_t stream)
{
  (void)in_sizes; (void)n_in; (void)out_size; (void)ws_size;
  const float* x    = (const float*)d_in[0];
  const float* wqkv = (const float*)d_in[1];
  const float* bqkv = (const float*)d_in[2];
  const float* wout = (const float*)d_in[3];
  const float* bout = (const float*)d_in[4];
  float* out = (float*)d_out;
  char* w = (char*)d_ws;

  u16* wqT = (u16*)(w + 0);          //  6.29 MB  w_qkv^T bf16 [3072][1024]
  u16* woT = (u16*)(w + 6291456);    //  2.10 MB  w_out^T bf16 [1024][1024]
  u16* xb  = (u16*)(w + 8388608);    // 33.55 MB  x bf16       (later: V^T)
  u16* vtb = xb;
  u16* qb  = (u16*)(w + 41943040);   // 33.55 MB  Q (b,h,p,d)
  u16* kb  = (u16*)(w + 75497472);   // 33.55 MB  K (b,h,p,d)
  u16* vb  = (u16*)(w + 109051904);  // 33.55 MB  V (b,h,p,d)  (later: Z (b,p,h,d))
  u16* zb  = vb;

  k_cvt <<<dim3(8192),    dim3(256), 0, stream>>>(x, xb, 2097152);
  k_cvtT<<<dim3(96, 32),  dim3(256), 0, stream>>>(wqkv, wqT, 1024, 3072);
  k_cvtT<<<dim3(32, 32),  dim3(256), 0, stream>>>(wout, woT, 1024, 1024);
  k_gemm<0><<<dim3(24, 128), dim3(256), 0, stream>>>(xb, wqT, bqkv, qb, kb, vb, nullptr);
  k_vt  <<<dim3(8, 512),  dim3(256), 0, stream>>>(vb, vtb);
  k_attn<<<dim3(1024),    dim3(256), 0, stream>>>(qb, kb, vtb, zb);
  k_gemm<1><<<dim3(8, 128), dim3(256), 0, stream>>>(zb, woT, bout, nullptr, nullptr, nullptr, out);
}